// Round 1
// baseline (234.368 us; speedup 1.0000x reference)
//
#include <hip/hip_runtime.h>
#include <hip/hip_fp16.h>

#define N_NODES 50000
#define N_EDGES 800000

typedef _Float16 half8 __attribute__((ext_vector_type(8)));
typedef _Float16 f16x4 __attribute__((ext_vector_type(4)));
typedef float floatx4 __attribute__((ext_vector_type(4)));

// ---------------------------------------------------------------------------
// setup: y=0 rowptr (lower_bound over sorted src); y=1 cast lw0 -> fp16;
//        y=2/3 fold lw1/lw2 (64x256) to planar K=192 fp16 matching agg layout
//        [i, ch*64+f], ch in {0:mean(heads0+1), 1:a2, 2:a3}.
// ---------------------------------------------------------------------------
__global__ __launch_bounds__(256) void setup_kernel(const int* __restrict__ src,
                                                    int* __restrict__ row_ptr,
                                                    const float* __restrict__ lw0,
                                                    const float* __restrict__ lw1,
                                                    const float* __restrict__ lw2,
                                                    _Float16* __restrict__ w0p,
                                                    _Float16* __restrict__ w1p,
                                                    _Float16* __restrict__ w2p) {
    int idx = blockIdx.x * 256 + threadIdx.x;
    if (blockIdx.y == 0) {
        if (idx > N_NODES) return;
        int lo = 0, hi = N_EDGES;
        while (lo < hi) {
            int mid = (lo + hi) >> 1;
            if (src[mid] < idx) lo = mid + 1; else hi = mid;
        }
        row_ptr[idx] = lo;
        return;
    }
    if (blockIdx.y == 1) {
        if (idx < 64 * 128) w0p[idx] = (_Float16)lw0[idx];
        return;
    }
    if (idx >= 64 * 192) return;
    int o = idx / 192, r = idx % 192;
    int ch = r >> 6, f = r & 63;
    const float* lw = (blockIdx.y == 2) ? lw1 : lw2;
    float v;
    if (ch == 0)      v = lw[o * 256 + f * 4 + 0] + lw[o * 256 + f * 4 + 1];
    else if (ch == 1) v = lw[o * 256 + f * 4 + 2];
    else              v = lw[o * 256 + f * 4 + 3];
    (blockIdx.y == 2 ? w1p : w2p)[idx] = (_Float16)v;
}

// ---------------------------------------------------------------------------
// lin via MFMA 16x16x32 f16 (layout verified R8). 4 waves, 16 rows x 64 cols
// per wave, fragments direct from global. TIn=float folds the x cast in.
// Score epilogue stores E = exp(score) (deferred-normalization softmax).
// ---------------------------------------------------------------------------
template <typename TIn, int K>
__global__ __launch_bounds__(256) void lin_kernel(const TIn* __restrict__ in,
                                                  const _Float16* __restrict__ w,
                                                  const float* __restrict__ b,
                                                  const float* __restrict__ aw,
                                                  _Float16* __restrict__ h,
                                                  float2* __restrict__ s, int n) {
    const int t = threadIdx.x;
    const int l = t & 63;
    const int wv = t >> 6;
    const int arow = l & 15;
    const int kg = l >> 4;
    const long rowbase = (long)blockIdx.x * 64 + wv * 16;
    long arow_g = rowbase + arow;
    if (arow_g >= n) arow_g = n - 1;

    floatx4 acc[4] = {};

    for (int kc = 0; kc < K; kc += 32) {
        const int ks = kc + kg * 8;
        half8 a;
        if (sizeof(TIn) == 4) {
            const TIn* ap = in + arow_g * K + ks;
            #pragma unroll
            for (int j = 0; j < 8; ++j) a[j] = (_Float16)ap[j];
        } else {
            a = *(const half8*)((const _Float16*)in + arow_g * K + ks);
        }
        #pragma unroll
        for (int ct = 0; ct < 4; ++ct) {
            half8 bb = *(const half8*)(w + (long)(ct * 16 + arow) * K + ks);
            acc[ct] = __builtin_amdgcn_mfma_f32_16x16x32_f16(a, bb, acc[ct], 0, 0, 0);
        }
    }

    const int c = l & 15;
    const int rq = l >> 4;
    float bias[4], a2c[4], a3c[4];
    #pragma unroll
    for (int ct = 0; ct < 4; ++ct) {
        int col = ct * 16 + c;
        bias[ct] = b[col];
        a2c[ct] = aw[2 * 128 + col] + aw[2 * 128 + 64 + col];
        a3c[ct] = aw[3 * 128 + col] + aw[3 * 128 + 64 + col];
    }
    #pragma unroll
    for (int r = 0; r < 4; ++r) {
        long row = rowbase + rq * 4 + r;
        bool ok = row < n;
        float q2 = 0.f, q3 = 0.f;
        _Float16 hv[4];
        #pragma unroll
        for (int ct = 0; ct < 4; ++ct) {
            float u = acc[ct][r] + bias[ct];
            u = u > 0.f ? u : 0.2f * u;
            q2 += u * a2c[ct];
            q3 += u * a3c[ct];
            hv[ct] = (_Float16)u;
        }
        if (ok) {
            #pragma unroll
            for (int ct = 0; ct < 4; ++ct) h[row * 64 + ct * 16 + c] = hv[ct];
        }
        #pragma unroll
        for (int o = 1; o < 16; o <<= 1) {
            q2 += __shfl_xor(q2, o);
            q3 += __shfl_xor(q3, o);
        }
        if (c == 0 && ok) s[row] = make_float2(__expf(q2), __expf(q3));
    }
}

// ---------------------------------------------------------------------------
// Single-pass aggregation, deferred softmax normalization, QUARTER-WAVE edge
// parallelism. Wave per node (4/block, grid 12500, no LDS).
// Lane: q = l>>4 (edge slot within 4-edge group), fl = l&15 (feature quad ->
// features fl*4..fl*4+3 via one f16x4 8B load; 16 lanes cover the 128B row).
// One VMEM instruction covers 4 edges.
// R13 change: 16-edge inner step (4 groups) instead of 8 (2 groups) — all 4
// h-gathers + 4 E-gathers issued before consumption to double MLP per wave
// (theory: agg is gather-latency-bound; chain dst->bpermute->gather->fma was
// only 2-deep). Edge-id distribution uses __shfl (ds_bpermute — per-lane
// index is legal; v_readlane with divergent index was the R12 bug).
// S2/S3 sum E per quarter; quarters partition edges -> xor-16/32 merge gives
// the true segment sums on every lane.
// ---------------------------------------------------------------------------
__global__ __launch_bounds__(256) void agg_kernel(const _Float16* __restrict__ hfeat,
                                                  const float2* __restrict__ E,
                                                  const int* __restrict__ dst,
                                                  const int* __restrict__ row_ptr,
                                                  _Float16* __restrict__ out_h,
                                                  float* __restrict__ out_f,
                                                  int final_layer, int n) {
    const int t = threadIdx.x;
    const int l = t & 63;
    const int i = blockIdx.x * 4 + (t >> 6);
    if (i >= n) return;
    const int r0 = row_ptr[i], r1 = row_ptr[i + 1];
    const int deg = r1 - r0;
    const int q = l >> 4;      // edge slot 0..3
    const int fl = l & 15;     // feature quad

    if (deg == 0) {
        if (!final_layer) {
            if (q < 3) *(f16x4*)(out_h + (long)i * 192 + q * 64 + fl * 4) =
                f16x4{(_Float16)0.f, (_Float16)0.f, (_Float16)0.f, (_Float16)0.f};
        } else if (q == 0) {
            *(floatx4*)(out_f + (long)i * 64 + fl * 4) = floatx4{0.f, 0.f, 0.f, 0.f};
        }
        return;
    }

    float am[4] = {}, a2[4] = {}, a3[4] = {};
    float S2 = 0.f, S3 = 0.f;

    for (int c0 = r0; c0 < r1; c0 += 64) {
        const int cn = min(64, r1 - c0);
        const int dl = dst[c0 + min(l, cn - 1)];   // coalesced edge-id load

        for (int jj = 0; jj < cn; jj += 16) {
            // four 4-edge groups; this lane handles edge jj + g*4 + q
            int dg[4]; float vg[4];
            #pragma unroll
            for (int g = 0; g < 4; ++g) {
                int e = jj + g * 4 + q;
                int ec = e < cn ? e : cn - 1;
                dg[g] = __shfl(dl, ec);            // ds_bpermute: per-lane idx OK
                vg[g] = e < cn ? 1.f : 0.f;
            }
            f16x4 hv[4]; float2 Ev[4];
            #pragma unroll
            for (int g = 0; g < 4; ++g) {
                hv[g] = *(const f16x4*)(hfeat + (long)dg[g] * 64 + fl * 4);
                Ev[g] = E[dg[g]];
            }
            #pragma unroll
            for (int g = 0; g < 4; ++g) {
                float vm = vg[g];
                float e2 = vm * Ev[g].x, e3 = vm * Ev[g].y;
                S2 += e2; S3 += e3;
                #pragma unroll
                for (int k = 0; k < 4; ++k) {
                    float hf = (float)hv[g][k];
                    am[k] += vm * hf;
                    a2[k] += e2 * hf;
                    a3[k] += e3 * hf;
                }
            }
        }
    }

    // merge quarters: lanes {fl, fl+16, fl+32, fl+48} all get the group sum
    #pragma unroll
    for (int o = 16; o < 64; o <<= 1) {
        #pragma unroll
        for (int k = 0; k < 4; ++k) {
            am[k] += __shfl_xor(am[k], o);
            a2[k] += __shfl_xor(a2[k], o);
            a3[k] += __shfl_xor(a3[k], o);
        }
        S2 += __shfl_xor(S2, o);
        S3 += __shfl_xor(S3, o);
    }

    const float inv_deg = 1.f / (float)deg;
    const float i2 = 1.f / S2, i3 = 1.f / S3;

    if (!final_layer) {
        if (q == 0) {
            f16x4 o0, o1, o2;
            #pragma unroll
            for (int k = 0; k < 4; ++k) {
                o0[k] = (_Float16)fmaxf(am[k] * inv_deg, 0.f);
                o1[k] = (_Float16)fmaxf(a2[k] * i2, 0.f);
                o2[k] = (_Float16)fmaxf(a3[k] * i3, 0.f);
            }
            *(f16x4*)(out_h + (long)i * 192 + fl * 4)       = o0;
            *(f16x4*)(out_h + (long)i * 192 + 64 + fl * 4)  = o1;
            *(f16x4*)(out_h + (long)i * 192 + 128 + fl * 4) = o2;
        }
    } else {
        if (q == 0) {
            floatx4 o;
            #pragma unroll
            for (int k = 0; k < 4; ++k)
                o[k] = fmaxf(0.5f * inv_deg * am[k] + 0.25f * (a2[k] * i2 + a3[k] * i3), 0.f);
            *(floatx4*)(out_f + (long)i * 64 + fl * 4) = o;
        }
    }
}

// ---------------------------------------------------------------------------
extern "C" void kernel_launch(void* const* d_in, const int* in_sizes, int n_in,
                              void* d_out, int out_size, void* d_ws, size_t ws_size,
                              hipStream_t stream) {
    const float* x = (const float*)d_in[0];
    const float* lw[3] = {(const float*)d_in[1], (const float*)d_in[5], (const float*)d_in[9]};
    const float* lb[3] = {(const float*)d_in[2], (const float*)d_in[6], (const float*)d_in[10]};
    const float* aw[3] = {(const float*)d_in[3], (const float*)d_in[7], (const float*)d_in[11]};
    const int* src = (const int*)d_in[13];
    const int* dst = (const int*)d_in[14];
    float* out = (float*)d_out;

    const int N = N_NODES;

    // ws layout: hA,hB: N*64 f16 | g: N*192 f16 | sA,sB: N float2
    //            | w0p 64*128 f16 | w1p,w2p 64*192 f16 | row_ptr N+1 int
    _Float16* hA = (_Float16*)d_ws;
    _Float16* hB = hA + (size_t)N * 64;
    _Float16* g  = hB + (size_t)N * 64;
    float2* sA = (float2*)(g + (size_t)N * 192);
    float2* sB = sA + N;
    _Float16* w0p = (_Float16*)(sB + N);
    _Float16* w1p = w0p + 64 * 128;
    _Float16* w2p = w1p + 64 * 192;
    int* row_ptr = (int*)(w2p + 64 * 192);

    const int lin_grid = (N + 63) / 64;      // 782
    const int node_grid = (N + 3) / 4;       // 12500

    setup_kernel<<<dim3(196, 4), 256, 0, stream>>>(src, row_ptr, lw[0], lw[1], lw[2],
                                                   w0p, w1p, w2p);

    // layer 0: x (fp32, cast inline) -> hA, sA(=E)
    lin_kernel<float, 128><<<lin_grid, 256, 0, stream>>>(x, w0p, lb[0], aw[0], hA, sA, N);

    // layer 0 agg -> g ; layer 1 lin: g -> hB, sB
    agg_kernel<<<node_grid, 256, 0, stream>>>(hA, sA, dst, row_ptr, g, out, 0, N);
    lin_kernel<_Float16, 192><<<lin_grid, 256, 0, stream>>>(g, w1p, lb[1], aw[1], hB, sB, N);

    // layer 1 agg -> g ; layer 2 lin: g -> hA, sA
    agg_kernel<<<node_grid, 256, 0, stream>>>(hB, sB, dst, row_ptr, g, out, 0, N);
    lin_kernel<_Float16, 192><<<lin_grid, 256, 0, stream>>>(g, w2p, lb[2], aw[2], hA, sA, N);

    // layer 2 final aggregation -> out (fp32)
    agg_kernel<<<node_grid, 256, 0, stream>>>(hA, sA, dst, row_ptr, g, out, 1, N);
}

// Round 2
// 199.926 us; speedup vs baseline: 1.1723x; 1.1723x over previous
//
#include <hip/hip_runtime.h>
#include <hip/hip_fp16.h>

#define N_NODES 50000
#define N_EDGES 800000

typedef _Float16 half8 __attribute__((ext_vector_type(8)));
typedef _Float16 f16x4 __attribute__((ext_vector_type(4)));
typedef float floatx4 __attribute__((ext_vector_type(4)));

// ---------------------------------------------------------------------------
// setup: y=0 rowptr (lower_bound over sorted src); y=1 cast lw0 -> fp16;
//        y=2/3 fold lw1/lw2 (64x256) to planar K=192 fp16 matching agg layout
//        [i, ch*64+f], ch in {0:mean(heads0+1), 1:a2, 2:a3}.
// ---------------------------------------------------------------------------
__global__ __launch_bounds__(256) void setup_kernel(const int* __restrict__ src,
                                                    int* __restrict__ row_ptr,
                                                    const float* __restrict__ lw0,
                                                    const float* __restrict__ lw1,
                                                    const float* __restrict__ lw2,
                                                    _Float16* __restrict__ w0p,
                                                    _Float16* __restrict__ w1p,
                                                    _Float16* __restrict__ w2p) {
    int idx = blockIdx.x * 256 + threadIdx.x;
    if (blockIdx.y == 0) {
        if (idx > N_NODES) return;
        int lo = 0, hi = N_EDGES;
        while (lo < hi) {
            int mid = (lo + hi) >> 1;
            if (src[mid] < idx) lo = mid + 1; else hi = mid;
        }
        row_ptr[idx] = lo;
        return;
    }
    if (blockIdx.y == 1) {
        if (idx < 64 * 128) w0p[idx] = (_Float16)lw0[idx];
        return;
    }
    if (idx >= 64 * 192) return;
    int o = idx / 192, r = idx % 192;
    int ch = r >> 6, f = r & 63;
    const float* lw = (blockIdx.y == 2) ? lw1 : lw2;
    float v;
    if (ch == 0)      v = lw[o * 256 + f * 4 + 0] + lw[o * 256 + f * 4 + 1];
    else if (ch == 1) v = lw[o * 256 + f * 4 + 2];
    else              v = lw[o * 256 + f * 4 + 3];
    (blockIdx.y == 2 ? w1p : w2p)[idx] = (_Float16)v;
}

// ---------------------------------------------------------------------------
// lin via MFMA 16x16x32 f16 (layout verified R8) — layer 0 only now
// (x fp32 -> hA, sA). 4 waves, 16 rows x 64 cols per wave.
// Score epilogue stores E = exp(score) (deferred-normalization softmax).
// ---------------------------------------------------------------------------
template <typename TIn, int K>
__global__ __launch_bounds__(256) void lin_kernel(const TIn* __restrict__ in,
                                                  const _Float16* __restrict__ w,
                                                  const float* __restrict__ b,
                                                  const float* __restrict__ aw,
                                                  _Float16* __restrict__ h,
                                                  float2* __restrict__ s, int n) {
    const int t = threadIdx.x;
    const int l = t & 63;
    const int wv = t >> 6;
    const int arow = l & 15;
    const int kg = l >> 4;
    const long rowbase = (long)blockIdx.x * 64 + wv * 16;
    long arow_g = rowbase + arow;
    if (arow_g >= n) arow_g = n - 1;

    floatx4 acc[4] = {};

    for (int kc = 0; kc < K; kc += 32) {
        const int ks = kc + kg * 8;
        half8 a;
        if (sizeof(TIn) == 4) {
            const TIn* ap = in + arow_g * K + ks;
            #pragma unroll
            for (int j = 0; j < 8; ++j) a[j] = (_Float16)ap[j];
        } else {
            a = *(const half8*)((const _Float16*)in + arow_g * K + ks);
        }
        #pragma unroll
        for (int ct = 0; ct < 4; ++ct) {
            half8 bb = *(const half8*)(w + (long)(ct * 16 + arow) * K + ks);
            acc[ct] = __builtin_amdgcn_mfma_f32_16x16x32_f16(a, bb, acc[ct], 0, 0, 0);
        }
    }

    const int c = l & 15;
    const int rq = l >> 4;
    float bias[4], a2c[4], a3c[4];
    #pragma unroll
    for (int ct = 0; ct < 4; ++ct) {
        int col = ct * 16 + c;
        bias[ct] = b[col];
        a2c[ct] = aw[2 * 128 + col] + aw[2 * 128 + 64 + col];
        a3c[ct] = aw[3 * 128 + col] + aw[3 * 128 + 64 + col];
    }
    #pragma unroll
    for (int r = 0; r < 4; ++r) {
        long row = rowbase + rq * 4 + r;
        bool ok = row < n;
        float q2 = 0.f, q3 = 0.f;
        _Float16 hv[4];
        #pragma unroll
        for (int ct = 0; ct < 4; ++ct) {
            float u = acc[ct][r] + bias[ct];
            u = u > 0.f ? u : 0.2f * u;
            q2 += u * a2c[ct];
            q3 += u * a3c[ct];
            hv[ct] = (_Float16)u;
        }
        if (ok) {
            #pragma unroll
            for (int ct = 0; ct < 4; ++ct) h[row * 64 + ct * 16 + c] = hv[ct];
        }
        #pragma unroll
        for (int o = 1; o < 16; o <<= 1) {
            q2 += __shfl_xor(q2, o);
            q3 += __shfl_xor(q3, o);
        }
        if (c == 0 && ok) s[row] = make_float2(__expf(q2), __expf(q3));
    }
}

// ---------------------------------------------------------------------------
// R14: fused layer kernel. Block = 256 thr = 4 waves = 16 nodes.
// Phase A (agg, QUARTER-PER-NODE): lane q=l>>4 owns node base+wv*4+q, fl=l&15
// owns features fl*4..+3. Edge ids broadcast within the quarter via __shfl
// (uniform loops over wave-max degree -> full exec mask, shfl always safe).
// E[dg] is quarter-uniform (HW broadcast); every lane accumulates the full
// S2/S3 for its node -> NO cross-lane merge at all. Per-edge instruction
// counts identical to the old wave-per-node scheme; padding waste drops
// (max-of-4-degrees vs per-node 16-slot rounding) and 28 merge shuffles go.
// Non-final: g row -> LDS (stride 200 f16: 16B-aligned for b128, 2-way banks).
// Phase B (lin, 16 rows x 64 cols): wave wv = col-slice ct, 6 MFMAs from LDS
// a-frags + global weight b-frags. Score q2/q3: in-quarter xor-reduce then
// 4-wave LDS reduce -> E=exp stored. g never touches HBM. Final: out_f direct.
// ---------------------------------------------------------------------------
template <int FINAL>
__global__ __launch_bounds__(256) void layer_kernel(const _Float16* __restrict__ hfeat,
                                                    const float2* __restrict__ E,
                                                    const int* __restrict__ dst,
                                                    const int* __restrict__ row_ptr,
                                                    const _Float16* __restrict__ w,
                                                    const float* __restrict__ b,
                                                    const float* __restrict__ aw,
                                                    _Float16* __restrict__ h_out,
                                                    float2* __restrict__ s_out,
                                                    float* __restrict__ out_f) {
    __shared__ _Float16 g_lds[16][200];
    __shared__ float2 spart[4][16];

    const int t = threadIdx.x;
    const int l = t & 63;
    const int wv = t >> 6;
    const int q = l >> 4;      // quarter id: phase A = node slot, phase B = k-group
    const int fl = l & 15;     // phase A = feature quad, phase B = row/col lane
    const int base = blockIdx.x * 16;
    const int i = base + wv * 4 + q;           // N_NODES % 16 == 0 -> always valid

    const int r0 = row_ptr[i];
    const int deg = row_ptr[i + 1] - r0;
    int md = deg;
    md = max(md, __shfl_xor(md, 16));
    md = max(md, __shfl_xor(md, 32));          // wave-uniform max degree

    float am[4] = {}, a2[4] = {}, a3[4] = {};
    float S2 = 0.f, S3 = 0.f;
    const int safew = deg > 0 ? r0 + deg - 1 : 0;   // clamp for padded lanes

    for (int c0 = 0; c0 < md; c0 += 16) {
        const int dl = dst[min(r0 + c0 + fl, safew)];  // 16 edge ids / quarter
        const int jn = min(16, md - c0);               // uniform inner bound
        for (int j = 0; j < jn; j += 4) {
            int dg[4]; float vm[4];
            #pragma unroll
            for (int g = 0; g < 4; ++g) {
                const int sl = j + g;                  // <= 15 always
                dg[g] = __shfl(dl, (q << 4) | sl);     // broadcast in-quarter
                vm[g] = (c0 + sl < deg) ? 1.f : 0.f;
            }
            f16x4 hv[4]; float2 Ev[4];
            #pragma unroll
            for (int g = 0; g < 4; ++g) {
                hv[g] = *(const f16x4*)(hfeat + (long)dg[g] * 64 + fl * 4);
                Ev[g] = E[dg[g]];                      // quarter-uniform bcast
            }
            #pragma unroll
            for (int g = 0; g < 4; ++g) {
                const float e2 = vm[g] * Ev[g].x, e3 = vm[g] * Ev[g].y;
                S2 += e2; S3 += e3;
                #pragma unroll
                for (int k = 0; k < 4; ++k) {
                    const float hf = (float)hv[g][k];
                    am[k] += vm[g] * hf;
                    a2[k] += e2 * hf;
                    a3[k] += e3 * hf;
                }
            }
        }
    }

    const float inv_deg = deg > 0 ? 1.f / (float)deg : 0.f;
    const float i2 = deg > 0 ? 1.f / S2 : 0.f;
    const float i3 = deg > 0 ? 1.f / S3 : 0.f;

    if (FINAL) {
        floatx4 o;
        #pragma unroll
        for (int k = 0; k < 4; ++k)
            o[k] = fmaxf(0.5f * inv_deg * am[k] + 0.25f * (a2[k] * i2 + a3[k] * i3), 0.f);
        *(floatx4*)(out_f + (long)i * 64 + fl * 4) = o;
        return;
    }

    // g row into LDS (all 16 lanes of the quarter write their own quads)
    {
        const int nl = wv * 4 + q;
        f16x4 o0, o1, o2;
        #pragma unroll
        for (int k = 0; k < 4; ++k) {
            o0[k] = (_Float16)fmaxf(am[k] * inv_deg, 0.f);
            o1[k] = (_Float16)fmaxf(a2[k] * i2, 0.f);
            o2[k] = (_Float16)fmaxf(a3[k] * i3, 0.f);
        }
        *(f16x4*)(&g_lds[nl][fl * 4])       = o0;
        *(f16x4*)(&g_lds[nl][64 + fl * 4])  = o1;
        *(f16x4*)(&g_lds[nl][128 + fl * 4]) = o2;
    }
    __syncthreads();

    // Phase B: lin for these 16 rows. Wave wv = cols wv*16..wv*16+15.
    floatx4 acc = {};
    #pragma unroll
    for (int kc = 0; kc < 192; kc += 32) {
        const int ks = kc + q * 8;
        half8 a = *(const half8*)(&g_lds[fl][ks]);
        half8 bb = *(const half8*)(w + (long)(wv * 16 + fl) * 192 + ks);
        acc = __builtin_amdgcn_mfma_f32_16x16x32_f16(a, bb, acc, 0, 0, 0);
    }

    const int col = wv * 16 + fl;
    const float bias = b[col];
    const float a2c = aw[2 * 128 + col] + aw[2 * 128 + 64 + col];
    const float a3c = aw[3 * 128 + col] + aw[3 * 128 + 64 + col];
    #pragma unroll
    for (int r = 0; r < 4; ++r) {
        const int row = q * 4 + r;
        float u = acc[r] + bias;
        u = u > 0.f ? u : 0.2f * u;
        h_out[(long)(base + row) * 64 + col] = (_Float16)u;
        float q2 = u * a2c, q3 = u * a3c;
        #pragma unroll
        for (int o = 1; o < 16; o <<= 1) {
            q2 += __shfl_xor(q2, o);
            q3 += __shfl_xor(q3, o);
        }
        if (fl == 0) spart[wv][row] = make_float2(q2, q3);
    }
    __syncthreads();
    if (t < 16) {
        const float2 p0 = spart[0][t], p1 = spart[1][t], p2 = spart[2][t], p3 = spart[3][t];
        s_out[base + t] = make_float2(__expf(p0.x + p1.x + p2.x + p3.x),
                                      __expf(p0.y + p1.y + p2.y + p3.y));
    }
}

// ---------------------------------------------------------------------------
extern "C" void kernel_launch(void* const* d_in, const int* in_sizes, int n_in,
                              void* d_out, int out_size, void* d_ws, size_t ws_size,
                              hipStream_t stream) {
    const float* x = (const float*)d_in[0];
    const float* lw[3] = {(const float*)d_in[1], (const float*)d_in[5], (const float*)d_in[9]};
    const float* lb[3] = {(const float*)d_in[2], (const float*)d_in[6], (const float*)d_in[10]};
    const float* aw[3] = {(const float*)d_in[3], (const float*)d_in[7], (const float*)d_in[11]};
    const int* src = (const int*)d_in[13];
    const int* dst = (const int*)d_in[14];
    float* out = (float*)d_out;

    const int N = N_NODES;

    // ws layout: hA,hB: N*64 f16 | sA,sB: N float2
    //            | w0p 64*128 f16 | w1p,w2p 64*192 f16 | row_ptr N+1 int
    _Float16* hA = (_Float16*)d_ws;
    _Float16* hB = hA + (size_t)N * 64;
    float2* sA = (float2*)(hB + (size_t)N * 64);
    float2* sB = sA + N;
    _Float16* w0p = (_Float16*)(sB + N);
    _Float16* w1p = w0p + 64 * 128;
    _Float16* w2p = w1p + 64 * 192;
    int* row_ptr = (int*)(w2p + 64 * 192);

    const int lin_grid = (N + 63) / 64;      // 782
    const int layer_grid = N / 16;           // 3125

    setup_kernel<<<dim3(196, 4), 256, 0, stream>>>(src, row_ptr, lw[0], lw[1], lw[2],
                                                   w0p, w1p, w2p);

    // layer 0 lin: x (fp32, cast inline) -> hA, sA(=E)
    lin_kernel<float, 128><<<lin_grid, 256, 0, stream>>>(x, w0p, lb[0], aw[0], hA, sA, N);

    // fused: layer 0 agg + layer 1 lin -> hB, sB
    layer_kernel<0><<<layer_grid, 256, 0, stream>>>(hA, sA, dst, row_ptr,
                                                    w1p, lb[1], aw[1], hB, sB, out);

    // fused: layer 1 agg + layer 2 lin -> hA, sA
    layer_kernel<0><<<layer_grid, 256, 0, stream>>>(hB, sB, dst, row_ptr,
                                                    w2p, lb[2], aw[2], hA, sA, out);

    // layer 2 final aggregation -> out (fp32)
    layer_kernel<1><<<layer_grid, 256, 0, stream>>>(hA, sA, dst, row_ptr,
                                                    w2p, lb[2], aw[2], hB, sB, out);
}